// Round 1
// baseline (181.994 us; speedup 1.0000x reference)
//
#include <hip/hip_runtime.h>
#include <math.h>

#define B 32
#define H 8
#define C 64
#define L 1024
#define HC (H * C)            // 512
#define K 6

#define SLICES 8
#define SLICE_L (L / SLICES)          // 128 l's per block
#define GROUPS1 16                    // 32-lane groups per 512-thread block
#define ROWS_PER_GROUP (HC / GROUPS1) // 32 rows each

// ---------------------------------------------------------------------------
// Stage 1 (fused): mean_value[b][l] = mean over 512 (h,c) rows of corr.
// 256 blocks = 32 b x 8 l-slices, 512 threads each (8 waves/CU vs the old
// 4 waves/CU -- the old config was 1 wave/SIMD, too thin to hide HBM
// latency on a pure streaming reduction). Each 32-lane group reads a 512 B
// contiguous float4 segment per row (fully coalesced), 32 rows per group,
// then an 8 KB LDS cross-group reduction.
// ---------------------------------------------------------------------------
__global__ __launch_bounds__(512) void mean_value_kernel(
    const float* __restrict__ corr, float* __restrict__ mean_value) {
    __shared__ float sacc[GROUPS1 * SLICE_L];   // 8 KB
    int blk = blockIdx.x;                       // 0..255
    int b = blk / SLICES;
    int s = blk % SLICES;
    int t = threadIdx.x;
    int g = t >> 5;                             // group 0..15
    int j = t & 31;                             // lane-in-group

    const float4* base =
        (const float4*)(corr + (size_t)b * HC * L + s * SLICE_L);
    float4 acc = make_float4(0.f, 0.f, 0.f, 0.f);
    #pragma unroll 8
    for (int i = 0; i < ROWS_PER_GROUP; ++i) {
        int r = g + GROUPS1 * i;                // rows g, g+16, ...
        float4 v = base[(size_t)r * (L / 4) + j];
        acc.x += v.x; acc.y += v.y; acc.z += v.z; acc.w += v.w;
    }
    ((float4*)sacc)[g * (SLICE_L / 4) + j] = acc;
    __syncthreads();

    if (t < SLICE_L) {
        float m = 0.f;
        #pragma unroll
        for (int g2 = 0; g2 < GROUPS1; ++g2) m += sacc[g2 * SLICE_L + t];
        mean_value[b * L + s * SLICE_L + t] = m * (1.0f / HC);
    }
}

// ---------------------------------------------------------------------------
// Stage 2: column mean over b, top-6 via wave-shuffle argmax (tie-break:
// smaller index, matching lax.top_k), then per-batch softmax.
// Single block of 1024 threads (16 waves); 2 barriers per top-k round.
// ---------------------------------------------------------------------------
__global__ __launch_bounds__(1024) void topk_softmax_kernel(
    const float* __restrict__ mean_value,
    float* __restrict__ tmp_corr,       // [B][K]
    int* __restrict__ index_out) {      // [K]
    __shared__ float wval[16];
    __shared__ int   widx[16];
    __shared__ int   sel[K];
    int t = threadIdx.x;
    int lane = t & 63;
    int wave = t >> 6;

    float s = 0.f;
    #pragma unroll
    for (int b = 0; b < B; ++b) s += mean_value[b * L + t];
    float cm = s * (1.0f / B);          // this thread's colmean value
    int   ci = t;

    for (int k = 0; k < K; ++k) {
        // wave-level argmax, tie-break smaller index
        float v = cm; int i = ci;
        #pragma unroll
        for (int off = 32; off >= 1; off >>= 1) {
            float v2 = __shfl_xor(v, off, 64);
            int   i2 = __shfl_xor(i, off, 64);
            if (v2 > v || (v2 == v && i2 < i)) { v = v2; i = i2; }
        }
        if (lane == 0) { wval[wave] = v; widx[wave] = i; }
        __syncthreads();
        if (wave == 0) {
            float v3 = (lane < 16) ? wval[lane] : -3.0e38f;
            int   i3 = (lane < 16) ? widx[lane] : 0x7fffffff;
            #pragma unroll
            for (int off = 8; off >= 1; off >>= 1) {
                float v2 = __shfl_xor(v3, off, 64);
                int   i2 = __shfl_xor(i3, off, 64);
                if (v2 > v3 || (v2 == v3 && i2 < i3)) { v3 = v2; i3 = i2; }
            }
            if (lane == 0) sel[k] = i3;
        }
        __syncthreads();
        if (ci == sel[k]) cm = -3.0e38f;   // remove from future rounds
    }

    if (t < K) index_out[t] = sel[t];
    if (t < B) {
        float w[K];
        float m = -3.0e38f;
        for (int k = 0; k < K; ++k) {
            w[k] = mean_value[t * L + sel[k]];
            m = fmaxf(m, w[k]);
        }
        float sum = 0.f;
        for (int k = 0; k < K; ++k) { w[k] = expf(w[k] - m); sum += w[k]; }
        float inv = 1.0f / sum;
        for (int k = 0; k < K; ++k) tmp_corr[t * K + k] = w[k] * inv;
    }
}

// ---------------------------------------------------------------------------
// Stage 3: out[b,h,c,l] = sum_k w[b,k] * values[b,h,c,(l+idx[k]) % L]
// One block per (b,h,c) row; row staged in LDS *twice* (8 KB) so the wrap
// "% L" disappears and each thread can own 4 CONSECUTIVE l's:
//   - 1 float4 global load, 2 float4 LDS writes (duplicate)
//   - per k: 4 adjacent dword LDS reads (compiler merges to ds_read2/b64)
//   - 1 float4 coalesced store (vs 4 scalar dword stores before)
// Accumulation order over k is unchanged (ascending), keeping numerics
// identical to the previous passing version.
// ---------------------------------------------------------------------------
__global__ __launch_bounds__(256) void agg_kernel(
    const float* __restrict__ values,
    const float* __restrict__ tmp_corr,
    const int* __restrict__ index,
    float* __restrict__ out) {
    __shared__ float row[2 * L];   // 8 KB, duplicated row
    __shared__ float ws[K];
    __shared__ int   is[K];
    int blk = blockIdx.x;                  // 0 .. B*H*C-1
    int b = blk / HC;
    int tid = threadIdx.x;

    float4 v = ((const float4*)(values + (size_t)blk * L))[tid];
    ((float4*)row)[tid] = v;
    ((float4*)row)[tid + 256] = v;         // duplicate: row[x] = vals[x % L]
    if (tid < K) { ws[tid] = tmp_corr[b * K + tid]; is[tid] = index[tid]; }
    __syncthreads();

    float w[K]; int d[K];
    #pragma unroll
    for (int k = 0; k < K; ++k) { w[k] = ws[k]; d[k] = is[k]; }

    int l0 = tid * 4;                      // 4 consecutive l's per thread
    float4 acc = make_float4(0.f, 0.f, 0.f, 0.f);
    #pragma unroll
    for (int k = 0; k < K; ++k) {
        const float* p = row + l0 + d[k];  // l0+d <= 1020+1023 < 2048
        acc.x += w[k] * p[0];
        acc.y += w[k] * p[1];
        acc.z += w[k] * p[2];
        acc.w += w[k] * p[3];
    }
    ((float4*)(out + (size_t)blk * L))[tid] = acc;
}

// ---------------------------------------------------------------------------
extern "C" void kernel_launch(void* const* d_in, const int* in_sizes, int n_in,
                              void* d_out, int out_size, void* d_ws, size_t ws_size,
                              hipStream_t stream) {
    const float* values = (const float*)d_in[0];
    const float* corr   = (const float*)d_in[1];
    float* out = (float*)d_out;

    // workspace layout
    float* mean_value = (float*)d_ws;                       // B*L floats
    float* tmp_corr   = mean_value + (size_t)B * L;         // B*K floats
    int*   index      = (int*)(tmp_corr + B * K);           // K ints

    mean_value_kernel<<<B * SLICES, 512, 0, stream>>>(corr, mean_value);
    topk_softmax_kernel<<<1, 1024, 0, stream>>>(mean_value, tmp_corr, index);
    agg_kernel<<<B * H * C, 256, 0, stream>>>(values, tmp_corr, index, out);
}

// Round 3
// 175.107 us; speedup vs baseline: 1.0393x; 1.0393x over previous
//
#include <hip/hip_runtime.h>
#include <math.h>

#define B 32
#define H 8
#define C 64
#define L 1024
#define HC (H * C)            // 512
#define K 6

#define SLICES 8
#define SLICE_L (L / SLICES)          // 128 l's per block
#define GROUPS1 32                    // 32-lane groups per 1024-thread block
#define ROWS_PER_GROUP (HC / GROUPS1) // 16 rows each

// ---------------------------------------------------------------------------
// Stage 1: mean_value[b][l] = mean over 512 (h,c) rows of corr.
// 256 blocks = 32 b x 8 l-slices, 1024 threads each (16 waves/CU). Each
// 32-lane group reads a 512 B contiguous float4 segment per row (fully
// coalesced), 16 rows per group, then a 16 KB LDS cross-group reduction.
// ---------------------------------------------------------------------------
__global__ __launch_bounds__(1024) void mean_value_kernel(
    const float* __restrict__ corr, float* __restrict__ mean_value) {
    __shared__ float sacc[GROUPS1 * SLICE_L];   // 16 KB
    int blk = blockIdx.x;                       // 0..255
    int b = blk / SLICES;
    int s = blk % SLICES;
    int t = threadIdx.x;
    int g = t >> 5;                             // group 0..31
    int j = t & 31;                             // lane-in-group

    const float4* base =
        (const float4*)(corr + (size_t)b * HC * L + s * SLICE_L);
    float4 acc = make_float4(0.f, 0.f, 0.f, 0.f);
    #pragma unroll 8
    for (int i = 0; i < ROWS_PER_GROUP; ++i) {
        int r = g + GROUPS1 * i;                // rows g, g+32, ...
        float4 v = base[(size_t)r * (L / 4) + j];
        acc.x += v.x; acc.y += v.y; acc.z += v.z; acc.w += v.w;
    }
    ((float4*)sacc)[g * (SLICE_L / 4) + j] = acc;
    __syncthreads();

    if (t < SLICE_L) {
        float m = 0.f;
        #pragma unroll
        for (int g2 = 0; g2 < GROUPS1; ++g2) m += sacc[g2 * SLICE_L + t];
        mean_value[b * L + s * SLICE_L + t] = m * (1.0f / HC);
    }
}

// ---------------------------------------------------------------------------
// Stage 2: column mean over b, top-6, per-batch softmax. Single barrier:
// 256 threads compute 4 colmeans each (float4, identical per-column
// ascending-b add order -> identical selection), stage to LDS, then wave 0
// ALONE does all K argmax rounds in registers (16 values per lane,
// shfl-xor reduce, tie-break smaller index) and the softmax (threads t<32
// are inside wave 0, sel[] is uniform in registers).
// ---------------------------------------------------------------------------
__global__ __launch_bounds__(256) void topk_softmax_kernel(
    const float* __restrict__ mean_value,
    float* __restrict__ tmp_corr,       // [B][K]
    int* __restrict__ index_out) {      // [K]
    __shared__ float cm[L];             // 4 KB colmeans
    int t = threadIdx.x;

    // phase A: colmeans for columns 4t..4t+3
    float4 s4 = make_float4(0.f, 0.f, 0.f, 0.f);
    #pragma unroll
    for (int b = 0; b < B; ++b) {
        float4 v = ((const float4*)(mean_value + (size_t)b * L))[t];
        s4.x += v.x; s4.y += v.y; s4.z += v.z; s4.w += v.w;
    }
    float4 c4 = make_float4(s4.x * (1.0f / B), s4.y * (1.0f / B),
                            s4.z * (1.0f / B), s4.w * (1.0f / B));
    ((float4*)cm)[t] = c4;
    __syncthreads();

    // phase B: wave 0 only, no barriers
    if (t < 64) {
        float val[16];
        #pragma unroll
        for (int q = 0; q < 4; ++q) {
            float4 v = ((float4*)cm)[t * 4 + q];
            val[q * 4 + 0] = v.x; val[q * 4 + 1] = v.y;
            val[q * 4 + 2] = v.z; val[q * 4 + 3] = v.w;
        }
        int sel[K];
        #pragma unroll
        for (int k = 0; k < K; ++k) {
            // local argmax over 16 (ascending, strict > keeps smaller idx)
            float best = -3.0e38f; int bi = 0x7fffffff;
            #pragma unroll
            for (int m = 0; m < 16; ++m) {
                if (val[m] > best) { best = val[m]; bi = t * 16 + m; }
            }
            // wave argmax, tie-break smaller index
            #pragma unroll
            for (int off = 32; off >= 1; off >>= 1) {
                float v2 = __shfl_xor(best, off, 64);
                int   i2 = __shfl_xor(bi, off, 64);
                if (v2 > best || (v2 == best && i2 < bi)) { best = v2; bi = i2; }
            }
            sel[k] = bi;                 // uniform across wave 0
            // removal (static indexing, predicated)
            #pragma unroll
            for (int m = 0; m < 16; ++m)
                if (t * 16 + m == bi) val[m] = -3.0e38f;
        }
        if (t == 0) {
            #pragma unroll
            for (int k = 0; k < K; ++k) index_out[k] = sel[k];
        }
        if (t < B) {                     // t<32: inside wave 0, sel in regs
            float w[K];
            float m = -3.0e38f;
            #pragma unroll
            for (int k = 0; k < K; ++k) {
                w[k] = mean_value[t * L + sel[k]];
                m = fmaxf(m, w[k]);
            }
            float sum = 0.f;
            #pragma unroll
            for (int k = 0; k < K; ++k) { w[k] = expf(w[k] - m); sum += w[k]; }
            float inv = 1.0f / sum;
            #pragma unroll
            for (int k = 0; k < K; ++k) tmp_corr[t * K + k] = w[k] * inv;
        }
    }
}

// ---------------------------------------------------------------------------
// Stage 3: out[b,h,c,l] = sum_k w[b,k] * values[b,h,c,(l+idx[k]) % L]
// One block per (b,h,c) row; row staged TWICE in LDS (8 KB) so the wrap
// disappears; each thread owns l = tid, tid+256, tid+512, tid+768:
//   - LDS reads are lane-consecutive dwords (2 lanes/bank = conflict-free)
//   - the +256-float offsets are compile-time immediates off one base
//     pointer per k (ds_read2st64-mergeable, 1024 B apart)
//   - stores are 4 coalesced dword stores (256 B/wave each)
// Accumulation order over k unchanged (ascending) -> numerics identical.
// ---------------------------------------------------------------------------
__global__ __launch_bounds__(256) void agg_kernel(
    const float* __restrict__ values,
    const float* __restrict__ tmp_corr,
    const int* __restrict__ index,
    float* __restrict__ out) {
    __shared__ float row[2 * L];   // 8 KB, duplicated row
    __shared__ float ws[K];
    __shared__ int   is[K];
    int blk = blockIdx.x;                  // 0 .. B*H*C-1
    int b = blk / HC;
    int tid = threadIdx.x;

    float4 v = ((const float4*)(values + (size_t)blk * L))[tid];
    ((float4*)row)[tid] = v;
    ((float4*)row)[tid + 256] = v;         // row[x] = vals[x % L], x < 2048
    if (tid < K) { ws[tid] = tmp_corr[b * K + tid]; is[tid] = index[tid]; }
    __syncthreads();

    float w[K]; int d[K];
    #pragma unroll
    for (int k = 0; k < K; ++k) { w[k] = ws[k]; d[k] = is[k]; }

    float a0 = 0.f, a1 = 0.f, a2 = 0.f, a3 = 0.f;
    #pragma unroll
    for (int k = 0; k < K; ++k) {
        const float* p = row + tid + d[k]; // tid+d+768 <= 2046 < 2048
        a0 += w[k] * p[0];
        a1 += w[k] * p[256];
        a2 += w[k] * p[512];
        a3 += w[k] * p[768];
    }
    float* orow = out + (size_t)blk * L;
    orow[tid]       = a0;
    orow[tid + 256] = a1;
    orow[tid + 512] = a2;
    orow[tid + 768] = a3;
}

// ---------------------------------------------------------------------------
extern "C" void kernel_launch(void* const* d_in, const int* in_sizes, int n_in,
                              void* d_out, int out_size, void* d_ws, size_t ws_size,
                              hipStream_t stream) {
    const float* values = (const float*)d_in[0];
    const float* corr   = (const float*)d_in[1];
    float* out = (float*)d_out;

    // workspace layout
    float* mean_value = (float*)d_ws;                       // B*L floats
    float* tmp_corr   = mean_value + (size_t)B * L;         // B*K floats
    int*   index      = (int*)(tmp_corr + B * K);           // K ints

    mean_value_kernel<<<B * SLICES, 1024, 0, stream>>>(corr, mean_value);
    topk_softmax_kernel<<<1, 256, 0, stream>>>(mean_value, tmp_corr, index);
    agg_kernel<<<B * H * C, 256, 0, stream>>>(values, tmp_corr, index, out);
}